// Round 3
// baseline (252.364 us; speedup 1.0000x reference)
//
#include <hip/hip_runtime.h>
#include <math.h>

// Problem constants (from reference setup_inputs)
#define S20 20
#define BB 1024
#define LL 512
#define HH 2
#define KK 2
#define NRATES 100000
#define NTERM 10   // highest Taylor power: P = sum_{n=0}^{NTERM} tau^n * Q^n/n!

// native 16B vector type (HIP float4 is a class — rejected by
// __builtin_nontemporal_store)
typedef float v4f __attribute__((ext_vector_type(4)));

__device__ __forceinline__ float softplusf(float x) {
    if (x > 20.f) return x;
    return log1pf(expf(x));
}

// ---------------------------------------------------------------------------
// Kernel 1: per (h,k) build normalized GTR rate matrix Q, then coefficient
// matrices C_n = Q^n / n! for n = 0..NTERM into d_ws:
//   qpow[ hk ][ n ][ i*20+j ],  hk = h*K + k   (4 * 11 * 400 floats = 70.4 KB)
// ---------------------------------------------------------------------------
__global__ __launch_bounds__(256) void build_qpow(
        const float* __restrict__ exch,   // (H,K,20,20)
        const float* __restrict__ eq,     // (H,K,20)
        float* __restrict__ qpow) {
    __shared__ float p[S20];
    __shared__ float row[S20];
    __shared__ float mue_s;
    __shared__ float Qm[400];
    __shared__ float bufA[400];
    __shared__ float bufB[400];

    const int hk = blockIdx.x;      // h*K + k
    const int tid = threadIdx.x;

    // equilibrium distribution p = softmax(eq[h,k,:])  (tiny: thread 0 serial)
    if (tid == 0) {
        const float* e = eq + hk * S20;
        float m = -1e30f;
        for (int i = 0; i < S20; i++) m = fmaxf(m, e[i]);
        float s = 0.f;
        for (int i = 0; i < S20; i++) { float v = expf(e[i] - m); p[i] = v; s += v; }
        float inv = 1.f / s;
        for (int i = 0; i < S20; i++) p[i] *= inv;
    }
    __syncthreads();

    // R_ij = softplus(0.5*(K_ij + K_ji)) off-diag, 0 on diag;  Qm = R_ij * p_j
    const float* ek = exch + hk * 400;
    for (int e = tid; e < 400; e += 256) {
        int i = e / 20, j = e % 20;
        float r = 0.f;
        if (i != j) r = softplusf(0.5f * (ek[i * 20 + j] + ek[j * 20 + i]));
        Qm[e] = r * p[j];
    }
    __syncthreads();

    if (tid < S20) {
        float s = 0.f;
        for (int j = 0; j < S20; j++) s += Qm[tid * 20 + j];
        row[tid] = s;
    }
    __syncthreads();
    if (tid == 0) {
        float m = 0.f;
        for (int i = 0; i < S20; i++) m += p[i] * row[i];
        mue_s = fmaxf(m, 1e-16f);
    }
    __syncthreads();

    const float inv_mue = 1.f / mue_s;
    for (int e = tid; e < 400; e += 256) {
        int i = e / 20, j = e % 20;
        float q = Qm[e];
        if (i == j) q -= row[i];     // diagonal: 0 - row_i
        Qm[e] = q * inv_mue;
    }
    __syncthreads();

    float* outb = qpow + (size_t)hk * (NTERM + 1) * 400;
    // C0 = I, C1 = Q
    for (int e = tid; e < 400; e += 256) {
        int i = e / 20, j = e % 20;
        outb[e]        = (i == j) ? 1.f : 0.f;
        outb[400 + e]  = Qm[e];
        bufA[e]        = Qm[e];
    }
    __syncthreads();

    float* cur = bufA;
    float* nxt = bufB;
    for (int n = 2; n <= NTERM; n++) {
        float invn = 1.f / (float)n;
        for (int e = tid; e < 400; e += 256) {
            int i = e / 20, j = e % 20;
            float acc = 0.f;
#pragma unroll
            for (int s = 0; s < S20; s++)
                acc += cur[i * 20 + s] * Qm[s * 20 + j];
            acc *= invn;
            nxt[e] = acc;
            outb[(size_t)n * 400 + e] = acc;
        }
        __syncthreads();
        float* t = cur; cur = nxt; nxt = t;
    }
}

// ---------------------------------------------------------------------------
// Kernel 2: 2048 blocks = (b, half). Each block handles 256 l-values of one b.
//  1. tau[h] = softplus(tau_kernel[h, rate_indices[b,h]])
//  2. P[h][k] = Horner(tau[h]; C_0..C_N)   (qpow is L2-resident, 70 KB)
//  3. z for each of 512 (l,h) rows — COALESCED: since 4|20, each float4 of the
//     input stream lies within exactly one row; the lane seeing the 1.0 writes
//     zb[row]. One-hot guarantees exactly one writer per row.
//  4. out[b,l,h,k,:] = P[h][k][z,:]  — contiguous float4 nontemporal stores.
// ---------------------------------------------------------------------------
__global__ __launch_bounds__(256) void anc_probs(
        const float* __restrict__ inputs,       // (B,L,H,20)
        const int*   __restrict__ rate_indices, // (B,H)
        const float* __restrict__ tau_kernel,   // (H,NRATES)
        const float* __restrict__ qpow,         // (4,NTERM+1,400)
        float* __restrict__ out) {              // (B,L,H,K,20)
    __shared__ __align__(16) float P[4 * 400];  // [h*2+k][i*20+j]
    __shared__ int zb[512];                     // rows r = l_local*H + h
    __shared__ float tauv[HH];

    const int blk  = blockIdx.x;
    const int b    = blk >> 1;
    const int half = blk & 1;
    const int tid  = threadIdx.x;

    if (tid < HH) {
        int ridx = rate_indices[b * HH + tid];
        tauv[tid] = softplusf(tau_kernel[tid * NRATES + ridx]);
    }
    __syncthreads();

    // P via Horner over the 11 coefficient matrices (L2-resident)
    for (int e = tid; e < 1600; e += 256) {
        int hk = e / 400;
        int h  = hk >> 1;
        int ij = e % 400;
        float tau = tauv[h];
        const float* cb = qpow + (size_t)hk * (NTERM + 1) * 400 + ij;
        float acc = cb[NTERM * 400];
#pragma unroll
        for (int n = NTERM - 1; n >= 0; n--)
            acc = acc * tau + cb[n * 400];
        P[e] = acc;
    }
    // (no barrier needed yet: P and zb are disjoint; single barrier below)

    // Coalesced one-hot scan: this half's input chunk = 10240 floats = 2560 f4.
    // float4 f covers elements [4f, 4f+4) of the chunk -> row f/5, z base (f%5)*4.
    const v4f* inB = (const v4f*)(inputs
                        + (size_t)b * (LL * HH * S20) + (size_t)half * 10240);
    for (int f = tid; f < 2560; f += 256) {
        v4f v = inB[f];
        int row   = f / 5;
        int zbase = (f % 5) * 4;
        if (v.x > 0.5f) zb[row] = zbase;
        if (v.y > 0.5f) zb[row] = zbase + 1;
        if (v.z > 0.5f) zb[row] = zbase + 2;
        if (v.w > 0.5f) zb[row] = zbase + 3;
    }
    __syncthreads();

    // Store this half's output chunk: 20480 floats = 5120 float4, coalesced.
    v4f* outB = (v4f*)(out + (size_t)b * (LL * HH * KK * S20)
                           + (size_t)half * 20480);
    for (int f = tid; f < 5120; f += 256) {
        int l  = f / 20;        // local l (0..255): 20 float4 per l
        int r  = f % 20;
        int h  = r / 10;        // 10 float4 per h
        int k  = (r % 10) / 5;  // 5 float4 per k
        int s4 = r % 5;
        int z  = zb[l * HH + h];
        // P row offset: z*20 + s4*4 is a multiple of 4 -> 16B aligned
        v4f v = *(const v4f*)(&P[(h * 2 + k) * 400 + z * 20 + s4 * 4]);
        __builtin_nontemporal_store(v, outB + f);
    }
}

extern "C" void kernel_launch(void* const* d_in, const int* in_sizes, int n_in,
                              void* d_out, int out_size, void* d_ws, size_t ws_size,
                              hipStream_t stream) {
    const float* inputs       = (const float*)d_in[0];
    const int*   rate_indices = (const int*)  d_in[1];
    const float* tau_kernel   = (const float*)d_in[2];
    const float* exch         = (const float*)d_in[3];
    const float* eq           = (const float*)d_in[4];
    float* out  = (float*)d_out;
    float* qpow = (float*)d_ws;   // needs 4*(NTERM+1)*400*4 = 70,400 B

    build_qpow<<<dim3(HH * KK), dim3(256), 0, stream>>>(exch, eq, qpow);
    anc_probs<<<dim3(BB * 2), dim3(256), 0, stream>>>(inputs, rate_indices,
                                                      tau_kernel, qpow, out);
}

// Round 4
// 251.304 us; speedup vs baseline: 1.0042x; 1.0042x over previous
//
#include <hip/hip_runtime.h>
#include <math.h>

// Problem constants (from reference setup_inputs)
#define S20 20
#define BB 1024
#define LL 512
#define HH 2
#define KK 2
#define NRATES 100000
#define NTERM 10   // highest Taylor power: P = sum_{n=0}^{NTERM} tau^n * Q^n/n!

typedef float v4f __attribute__((ext_vector_type(4)));

__device__ __forceinline__ float softplusf(float x) {
    if (x > 20.f) return x;
    return log1pf(expf(x));
}

// ---------------------------------------------------------------------------
// Kernel 1: per (h,k) build normalized GTR rate matrix Q, then coefficient
// matrices C_n = Q^n / n! for n = 0..NTERM into d_ws:
//   qpow[ hk ][ n ][ i*20+j ],  hk = h*K + k   (4 * 11 * 400 floats = 70.4 KB)
// ---------------------------------------------------------------------------
__global__ __launch_bounds__(256) void build_qpow(
        const float* __restrict__ exch,   // (H,K,20,20)
        const float* __restrict__ eq,     // (H,K,20)
        float* __restrict__ qpow) {
    __shared__ float p[S20];
    __shared__ float row[S20];
    __shared__ float mue_s;
    __shared__ float Qm[400];
    __shared__ float bufA[400];
    __shared__ float bufB[400];

    const int hk = blockIdx.x;      // h*K + k
    const int tid = threadIdx.x;

    if (tid == 0) {
        const float* e = eq + hk * S20;
        float m = -1e30f;
        for (int i = 0; i < S20; i++) m = fmaxf(m, e[i]);
        float s = 0.f;
        for (int i = 0; i < S20; i++) { float v = expf(e[i] - m); p[i] = v; s += v; }
        float inv = 1.f / s;
        for (int i = 0; i < S20; i++) p[i] *= inv;
    }
    __syncthreads();

    const float* ek = exch + hk * 400;
    for (int e = tid; e < 400; e += 256) {
        int i = e / 20, j = e % 20;
        float r = 0.f;
        if (i != j) r = softplusf(0.5f * (ek[i * 20 + j] + ek[j * 20 + i]));
        Qm[e] = r * p[j];
    }
    __syncthreads();

    if (tid < S20) {
        float s = 0.f;
        for (int j = 0; j < S20; j++) s += Qm[tid * 20 + j];
        row[tid] = s;
    }
    __syncthreads();
    if (tid == 0) {
        float m = 0.f;
        for (int i = 0; i < S20; i++) m += p[i] * row[i];
        mue_s = fmaxf(m, 1e-16f);
    }
    __syncthreads();

    const float inv_mue = 1.f / mue_s;
    for (int e = tid; e < 400; e += 256) {
        int i = e / 20, j = e % 20;
        float q = Qm[e];
        if (i == j) q -= row[i];
        Qm[e] = q * inv_mue;
    }
    __syncthreads();

    float* outb = qpow + (size_t)hk * (NTERM + 1) * 400;
    for (int e = tid; e < 400; e += 256) {
        int i = e / 20, j = e % 20;
        outb[e]        = (i == j) ? 1.f : 0.f;
        outb[400 + e]  = Qm[e];
        bufA[e]        = Qm[e];
    }
    __syncthreads();

    float* cur = bufA;
    float* nxt = bufB;
    for (int n = 2; n <= NTERM; n++) {
        float invn = 1.f / (float)n;
        for (int e = tid; e < 400; e += 256) {
            int i = e / 20, j = e % 20;
            float acc = 0.f;
#pragma unroll
            for (int s = 0; s < S20; s++)
                acc += cur[i * 20 + s] * Qm[s * 20 + j];
            acc *= invn;
            nxt[e] = acc;
            outb[(size_t)n * 400 + e] = acc;
        }
        __syncthreads();
        float* t = cur; cur = nxt; nxt = t;
    }
}

// ---------------------------------------------------------------------------
// Kernel 2: 2048 blocks = (b, half); 256 threads; ONE barrier total.
//  - tau computed redundantly per-thread (same-address loads broadcast in L1)
//  - Horner: 7 elems/thread, 11 independent L2 loads each (77 in flight)
//  - read phase software-pipelined: 10 v4f loads in flight per thread
//  - store phase: incremental (l,r) index math, plain coalesced f4 stores
// ---------------------------------------------------------------------------
__global__ __launch_bounds__(256) void anc_probs(
        const float* __restrict__ inputs,       // (B,L,H,20)
        const int*   __restrict__ rate_indices, // (B,H)
        const float* __restrict__ tau_kernel,   // (H,NRATES)
        const float* __restrict__ qpow,         // (4,NTERM+1,400)
        float* __restrict__ out) {              // (B,L,H,K,20)
    __shared__ __align__(16) float P[4 * 400];  // [h*2+k][i*20+j]
    __shared__ int zb[512];                     // rows r = l_local*H + h

    const int blk  = blockIdx.x;
    const int b    = blk >> 1;
    const int half = blk & 1;
    const int tid  = threadIdx.x;

    // tau per-thread (no LDS, no barrier): same address across lanes -> bcast
    const float tau0 = softplusf(tau_kernel[rate_indices[b * HH + 0]]);
    const float tau1 = softplusf(tau_kernel[NRATES + rate_indices[b * HH + 1]]);

    // Issue the 10 input loads FIRST so they overlap the Horner compute.
    const v4f* inB = (const v4f*)(inputs
                        + (size_t)b * (LL * HH * S20) + (size_t)half * 10240);
    v4f vv[10];
#pragma unroll
    for (int q = 0; q < 10; q++) vv[q] = inB[tid + 256 * q];

    // P via Horner over the 11 coefficient matrices (L2-resident, 70 KB)
#pragma unroll
    for (int kk = 0; kk < 7; kk++) {
        int e = tid + 256 * kk;
        if (kk == 6 && tid >= 64) break;        // 1600 = 6*256 + 64
        int hk = e / 400;
        float tau = (hk >= 2) ? tau1 : tau0;
        const float* cb = qpow + (size_t)hk * (NTERM + 1) * 400 + (e % 400);
        float acc = cb[NTERM * 400];
#pragma unroll
        for (int n = NTERM - 1; n >= 0; n--)
            acc = acc * tau + cb[n * 400];
        P[e] = acc;
    }

    // One-hot scan (coalesced, loads already in flight): f = tid + 256q covers
    // elements [4f,4f+4) -> row f/5, z base (f%5)*4. Exactly one writer/row.
#pragma unroll
    for (int q = 0; q < 10; q++) {
        int f = tid + 256 * q;
        v4f v = vv[q];
        int row   = f / 5;
        int zbase = (f % 5) * 4;
        if (v.x > 0.5f) zb[row] = zbase;
        if (v.y > 0.5f) zb[row] = zbase + 1;
        if (v.z > 0.5f) zb[row] = zbase + 2;
        if (v.w > 0.5f) zb[row] = zbase + 3;
    }
    __syncthreads();                            // the ONLY barrier

    // Store 5120 f4 (20480 floats), coalesced. f = tid + 256*it.
    // l = f/20, r = f%20; per iter: r += 16 (mod 20), l += 12 or 13.
    v4f* outB = (v4f*)(out + (size_t)b * (LL * HH * KK * S20)
                           + (size_t)half * 20480);
    int l = tid / 20;
    int r = tid % 20;
#pragma unroll
    for (int it = 0; it < 20; it++) {
        int f  = tid + 256 * it;
        int h  = (r >= 10) ? 1 : 0;
        int r2 = r - 10 * h;
        int k  = (r2 >= 5) ? 1 : 0;
        int s4 = r2 - 5 * k;
        int z  = zb[l * HH + h];
        v4f v = *(const v4f*)(&P[(h * 2 + k) * 400 + z * 20 + s4 * 4]);
        outB[f] = v;
        // advance (l, r) by 256 f4 = 12*20 + 16
        r += 16;
        if (r >= 20) { r -= 20; l += 13; } else { l += 12; }
    }
}

extern "C" void kernel_launch(void* const* d_in, const int* in_sizes, int n_in,
                              void* d_out, int out_size, void* d_ws, size_t ws_size,
                              hipStream_t stream) {
    const float* inputs       = (const float*)d_in[0];
    const int*   rate_indices = (const int*)  d_in[1];
    const float* tau_kernel   = (const float*)d_in[2];
    const float* exch         = (const float*)d_in[3];
    const float* eq           = (const float*)d_in[4];
    float* out  = (float*)d_out;
    float* qpow = (float*)d_ws;   // needs 4*(NTERM+1)*400*4 = 70,400 B

    build_qpow<<<dim3(HH * KK), dim3(256), 0, stream>>>(exch, eq, qpow);
    anc_probs<<<dim3(BB * 2), dim3(256), 0, stream>>>(inputs, rate_indices,
                                                      tau_kernel, qpow, out);
}